// Round 21
// baseline (161.474 us; speedup 1.0000x reference)
//
#include <hip/hip_runtime.h>
#include <stdint.h>

// Causal GQA attention fwd, B=2 T=2048 H=32 HKV=8 D=128, fp32 in/out, bf16 MFMA compute.
//
// Round 21: PRODUCER/CONSUMER wave specialization. 512-thr blocks: waves 0-3 compute
// QK^T+softmax and hand P (bf16, packed PV-B-operand order) to waves 4-7 via LDS;
// consumers run PV into acc[4] and store. Total MFMA/VALU per tile unchanged from r14
// (no duplication, unlike r20's d-split), but each PATH's register frame fits ~100
// <= 128 -> 16 waves/CU (r20 proved the occupancy bucket; r14 was stuck at 144 regs).
// P handoff: per-pair 2KB double-buffered LDS, 1-tile lag; lgkmcnt(0)+raw barrier
// per tile orders write->read; contiguous b128 P layout = conflict-free.
// K triple-buffer (producer, lag 0), V quad-buffer (consumer, lag 1). vmcnt(2).
//
//   cvt_k: K fp32 [B,T,8,128] -> Kb bf16 [B,8,T,128] with row (t&~31)|pi(t&31),
//          16B-slot s stored at s^(row&7)   (pi => P lands in PV B-operand order)
//   cvt_v: V fp32 [B,T,8,128] -> VTb bf16 [B,8,tile32(64)][p(64)=d-pair][slot(8)][e(8)],
//          slot=(d&1)*4+oct stored at slot^(p&7)
//   attn:  1024 blocks x 512 thr, qtile16 descending (LPT), kvh = XCD (KV L2-pinned).
//          Static-max softmax (scores log2-bounded).

typedef __attribute__((ext_vector_type(8))) __bf16 bf16x8;
typedef __attribute__((ext_vector_type(16))) float f32x16;

#define QSCALE (0.08838834764831845f * 1.4426950408889634f)

__host__ __device__ inline unsigned pi32(unsigned x) {   // swap quads 1<->2 per 16
    unsigned q2 = (x >> 2) & 3u;
    return (q2 == 1u || q2 == 2u) ? (x ^ 12u) : x;
}

// ---------------- pre-pass: K convert + pi row-permute + swizzle ----------------
__global__ __launch_bounds__(256) void cvt_k(const float* __restrict__ k,
                                             unsigned short* __restrict__ kb) {
    unsigned tid = blockIdx.x * 256u + threadIdx.x;
    unsigned s = tid & 15u;
    unsigned h = (tid >> 4) & 7u;
    unsigned t = (tid >> 7) & 2047u;
    unsigned b = tid >> 18;
    const float4* src = (const float4*)(k + (size_t)tid * 8u);
    float4 f0 = src[0], f1 = src[1];
    bf16x8 r;
    r[0] = (__bf16)f0.x; r[1] = (__bf16)f0.y; r[2] = (__bf16)f0.z; r[3] = (__bf16)f0.w;
    r[4] = (__bf16)f1.x; r[5] = (__bf16)f1.y; r[6] = (__bf16)f1.z; r[7] = (__bf16)f1.w;
    unsigned tp = (t & ~31u) | pi32(t & 31u);
    size_t o = ((size_t)((b * 8u + h) * 2048u + tp) * 16u + (s ^ (tp & 7u))) * 8u;
    *(bf16x8*)(kb + o) = r;
}

// ---------------- pre-pass: V convert + transpose to 32-kv tiles ----------------
__global__ __launch_bounds__(256) void cvt_v(const float* __restrict__ v,
                                             unsigned short* __restrict__ vtb) {
    unsigned tid = blockIdx.x * 256u + threadIdx.x;    // 524288 total
    unsigned d = tid & 127u;            // fast-varying => coalesced reads
    unsigned oct = (tid >> 7) & 3u;
    unsigned tile = (tid >> 9) & 63u;
    unsigned kvh = (tid >> 15) & 7u;
    unsigned b = tid >> 18;
    const float* src = v + ((size_t)(b * 2048u + tile * 32u + oct * 8u) * 8u + kvh) * 128u + d;
    bf16x8 r;
#pragma unroll
    for (int e = 0; e < 8; ++e) r[e] = (__bf16)src[(size_t)e * 1024u];
    unsigned p = d >> 1;
    unsigned slot = (d & 1u) * 4u + oct;
    size_t off = (size_t)(b * 8u + kvh) * 262144u + (size_t)tile * 4096u
               + (p * 8u + (slot ^ (p & 7u))) * 8u;
    *(bf16x8*)(vtb + off) = r;
}

// ---------------- main attention kernel ----------------
__device__ inline void load16_lds(const void* g, void* l) {
    __builtin_amdgcn_global_load_lds(
        (__attribute__((address_space(1))) void*)(g),
        (__attribute__((address_space(3))) void*)(l), 16, 0, 0);
}

union BW2 { unsigned u; __bf16 h[2]; };
union BW8 { unsigned u[4]; bf16x8 v; };

__global__ __launch_bounds__(512, 2) void attn_fwd(const float* __restrict__ qg,
                                                   const unsigned short* __restrict__ kb,
                                                   const unsigned short* __restrict__ vtb,
                                                   float* __restrict__ outg) {
    __shared__ __align__(16) unsigned short K0[32*128], K1[32*128], K2[32*128];       // 24 KB
    __shared__ __align__(16) unsigned short V0[64*64], V1[64*64], V2[64*64], V3[64*64]; // 32 KB
    __shared__ __align__(16) unsigned short Pl[2][4][1024];                           // 16 KB
    __shared__ float lsum[4][64];                                                     // 1 KB

    // Decode: bid&7 = XCD = kvh (KV L2-pinned); qtile16 DESCENDING (LPT).
    int bid = blockIdx.x;
    int kvh = bid & 7;
    int pos = bid >> 3;                // 0..127
    int qt = 15 - (pos >> 3);
    int sub = pos & 7;
    int b = sub & 1;
    int h = kvh * 4 + (sub >> 1);

    int tid = threadIdx.x;
    int lane = tid & 63;
    int w = tid >> 6;                  // 0..7
    int pw = w & 3;                    // pair index
    bool isP = (w < 4);
    int lq = lane & 31;
    int hi = lane >> 5;
    int q0w = qt * 128 + pw * 32;      // pair's q rows
    int nt = 4 * (qt + 1);

    const unsigned short* kT = kb + (size_t)(b * 8 + kvh) * 262144u;
    const unsigned short* vT = vtb + (size_t)(b * 8 + kvh) * 262144u;

    auto stage = [&](int t, unsigned short* kd, unsigned short* vd) {
        const char* ks = (const char*)(kT + (size_t)t * 4096u);   // 8 KB
        const char* vs = (const char*)(vT + (size_t)t * 4096u);   // 8 KB
        load16_lds(ks + tid * 16, kd + tid * 8);
        load16_lds(vs + tid * 16, vd + tid * 8);
    };

    // Producer: Q loads FIRST (so compiler's qf-wait leaves stage loads in flight).
    bf16x8 qf[8];
    if (isP) {
        const float* qp = qg + ((size_t)(b * 2048 + q0w + lq) * 32u + h) * 128u;
#pragma unroll
        for (int c = 0; c < 8; ++c) {
            int d0 = c * 16 + hi * 8;
            float4 f0 = *(const float4*)(qp + d0);
            float4 f1 = *(const float4*)(qp + d0 + 4);
            qf[c][0] = (__bf16)(f0.x * QSCALE); qf[c][1] = (__bf16)(f0.y * QSCALE);
            qf[c][2] = (__bf16)(f0.z * QSCALE); qf[c][3] = (__bf16)(f0.w * QSCALE);
            qf[c][4] = (__bf16)(f1.x * QSCALE); qf[c][5] = (__bf16)(f1.y * QSCALE);
            qf[c][6] = (__bf16)(f1.z * QSCALE); qf[c][7] = (__bf16)(f1.w * QSCALE);
        }
    }

    stage(0, K0, V0);
    stage(1, K1, V1);

    f32x16 acc[4];
    if (!isP) {
#pragma unroll
        for (int dt = 0; dt < 4; ++dt)
#pragma unroll
            for (int r = 0; r < 16; ++r) acc[dt][r] = 0.f;
    }
    float lrun = 0.f;

    unsigned short *k0 = K0, *k1 = K1, *k2 = K2;          // K(t), K(t+1), K(t+2 target)
    unsigned short *vm1 = V3, *v0 = V0, *v1 = V1, *v2 = V2; // V(t-1), V(t), V(t+1), V(t+2 target)

    for (int t = 0; t <= nt; ++t) {
        if (t + 1 < nt) { asm volatile("s_waitcnt vmcnt(2)" ::: "memory"); }
        else            { asm volatile("s_waitcnt vmcnt(0)" ::: "memory"); }
        asm volatile("s_waitcnt lgkmcnt(0)" ::: "memory");   // P handoff ordering
        __builtin_amdgcn_s_barrier();
        if (t + 2 < nt) stage(t + 2, k2, v2);
        if (isP) {
            int kv0 = t * 32;
            if (kv0 <= q0w + 31) {                 // wave-uniform (implies t < nt)
                // ---- QK^T (8 MFMA), K from k0 (pi-permuted rows)
                f32x16 st0;
#pragma unroll
                for (int r = 0; r < 16; ++r) st0[r] = 0.f;
                __builtin_amdgcn_s_setprio(1);
#pragma unroll
                for (int c = 0; c < 8; ++c) {
                    bf16x8 kf = *(const bf16x8*)&k0[lq * 128 + (((2 * c + hi) ^ (lq & 7)) << 3)];
                    st0 = __builtin_amdgcn_mfma_f32_32x32x16_bf16(kf, qf[c], st0, 0, 0, 0);
                }
                __builtin_amdgcn_s_setprio(0);
                // ---- diagonal mask (actual kv = pi(row))
                if (kv0 == q0w) {
#pragma unroll
                    for (int r = 0; r < 16; ++r) {
                        int kvl = (r & 3) + 8 * (r >> 2) + 4 * hi;
                        int q2 = (kvl >> 2) & 3;
                        int kva = (q2 == 1 || q2 == 2) ? (kvl ^ 12) : kvl;
                        if (kva > lq) st0[r] = -1e30f;
                    }
                }
                // ---- static-max softmax
#pragma unroll
                for (int r = 0; r < 16; ++r) st0[r] = exp2f(st0[r]);
                // ---- pack P (already PV B-operand order) and hand to consumer
                BW8 pb0, pb1;
#pragma unroll
                for (int i = 0; i < 4; ++i) {
                    BW2 a; a.h[0] = (__bf16)st0[2 * i];     a.h[1] = (__bf16)st0[2 * i + 1];
                    BW2 c; c.h[0] = (__bf16)st0[8 + 2 * i]; c.h[1] = (__bf16)st0[9 + 2 * i];
                    pb0.u[i] = a.u; pb1.u[i] = c.u;
                }
                *(bf16x8*)&Pl[t & 1][pw][lane * 8] = pb0.v;
                *(bf16x8*)&Pl[t & 1][pw][512 + lane * 8] = pb1.v;
                // ---- row-sum
                float s8[8];
#pragma unroll
                for (int i = 0; i < 8; ++i) s8[i] = st0[2 * i] + st0[2 * i + 1];
#pragma unroll
                for (int i = 0; i < 4; ++i) s8[i] = s8[i] + s8[i + 4];
                lrun += (s8[0] + s8[1]) + (s8[2] + s8[3]);
            }
        } else {
            int tp = t - 1;
            if (tp >= 0 && tp * 32 <= q0w + 31) {
                // ---- PV (8 MFMA): P from Pl[tp&1][pw], V from vm1 = V(t-1)
                BW8 pb0, pb1;
                pb0.v = *(const bf16x8*)&Pl[tp & 1][pw][lane * 8];
                pb1.v = *(const bf16x8*)&Pl[tp & 1][pw][512 + lane * 8];
                __builtin_amdgcn_s_setprio(1);
#pragma unroll
                for (int dt = 0; dt < 4; ++dt) {
                    int drow = dt * 32 + lq;
                    int pp = drow >> 1;
                    int s0 = (drow & 1) * 4 + hi;
                    int s1 = s0 + 2;
                    bf16x8 vf0 = *(const bf16x8*)&vm1[pp * 64 + ((s0 ^ (pp & 7)) << 3)];
                    acc[dt] = __builtin_amdgcn_mfma_f32_32x32x16_bf16(vf0, pb0.v, acc[dt], 0, 0, 0);
                    bf16x8 vf1 = *(const bf16x8*)&vm1[pp * 64 + ((s1 ^ (pp & 7)) << 3)];
                    acc[dt] = __builtin_amdgcn_mfma_f32_32x32x16_bf16(vf1, pb1.v, acc[dt], 0, 0, 0);
                }
                __builtin_amdgcn_s_setprio(0);
            }
        }
        // rotate buffers: K by 3, V by 4
        unsigned short* tk = k0; k0 = k1; k1 = k2; k2 = tk;
        unsigned short* tv = vm1; vm1 = v0; v0 = v1; v1 = v2; v2 = tv;
    }

    // ---- epilogue: producer publishes row sums; consumer scales + stores
    if (isP) {
        lrun += __shfl_xor(lrun, 32);
        lsum[pw][lane] = lrun;
    }
    asm volatile("s_waitcnt lgkmcnt(0)" ::: "memory");
    __builtin_amdgcn_s_barrier();
    if (!isP) {
        float il = 1.0f / lsum[pw][lane];
        float* ob = outg + ((size_t)(b * 2048 + q0w + lq) * 32u + h) * 128u;
#pragma unroll
        for (int dt = 0; dt < 4; ++dt)
#pragma unroll
            for (int rq = 0; rq < 4; ++rq) {
                int d = dt * 32 + rq * 8 + hi * 4;
                float4 o4 = { acc[dt][rq * 4 + 0] * il, acc[dt][rq * 4 + 1] * il,
                              acc[dt][rq * 4 + 2] * il, acc[dt][rq * 4 + 3] * il };
                *(float4*)(ob + d) = o4;
            }
    }
}

extern "C" void kernel_launch(void* const* d_in, const int* in_sizes, int n_in,
                              void* d_out, int out_size, void* d_ws, size_t ws_size,
                              hipStream_t stream) {
    const float* q = (const float*)d_in[0];
    const float* k = (const float*)d_in[1];
    const float* v = (const float*)d_in[2];
    float* out = (float*)d_out;
    unsigned short* kbuf = (unsigned short*)d_ws;                    // 8.4 MB bf16 K (pi rows)
    unsigned short* vbuf = kbuf + (size_t)2 * 8 * 2048 * 128;        // 8.4 MB bf16 V^T (32-kv tiles)
    cvt_k<<<2048, 256, 0, stream>>>(k, kbuf);
    cvt_v<<<2048, 256, 0, stream>>>(v, vbuf);
    attn_fwd<<<1024, 512, 0, stream>>>(q, kbuf, vbuf, out);
}

// Round 22
// 121.951 us; speedup vs baseline: 1.3241x; 1.3241x over previous
//
#include <hip/hip_runtime.h>
#include <stdint.h>

// Causal GQA attention fwd, B=2 T=2048 H=32 HKV=8 D=128, fp32 in/out, bf16 MFMA compute.
//
// Round 22: r14 inner math with PAIR-TILE iterations: tiles (2u,2u+1) per loop pass
// from one 32KB K+V buffer-pair (double-buffered, 64KB LDS; 2 blocks/CU — VGPR
// already caps at 8 waves/CU so no occupancy loss). ONE vmcnt(0) + ONE raw barrier
// per TWO tiles (halves the barrier convoy); stagePair(u+1) post-barrier gets a
// 2-tile compute phase of cover; QK(B) adjacent to softmax(A) lets the compiler
// overlap MFMA with VALU in-wave (r13's goal at +16 regs instead of +44).
//
//   cvt_k: K fp32 [B,T,8,128] -> Kb bf16 [B,8,T,128] with row (t&~31)|pi(t&31),
//          16B-slot s stored at s^(row&7)   (pi => zero-exchange P)
//   cvt_v: V fp32 [B,T,8,128] -> VTb bf16 [B,8,tile32(64)][p(64)=d-pair][slot(8)][e(8)],
//          slot=(d&1)*4+oct stored at slot^(p&7)
//   attn:  1024 blocks x 256 thr (4 waves x 32 q rows), qtile16 descending (LPT),
//          kvh = XCD (KV L2-pinned). Static-max softmax (scores log2-bounded).

typedef __attribute__((ext_vector_type(8))) __bf16 bf16x8;
typedef __attribute__((ext_vector_type(16))) float f32x16;

#define QSCALE (0.08838834764831845f * 1.4426950408889634f)

__host__ __device__ inline unsigned pi32(unsigned x) {   // swap quads 1<->2 per 16
    unsigned q2 = (x >> 2) & 3u;
    return (q2 == 1u || q2 == 2u) ? (x ^ 12u) : x;
}

// ---------------- pre-pass: K convert + pi row-permute + swizzle ----------------
__global__ __launch_bounds__(256) void cvt_k(const float* __restrict__ k,
                                             unsigned short* __restrict__ kb) {
    unsigned tid = blockIdx.x * 256u + threadIdx.x;
    unsigned s = tid & 15u;
    unsigned h = (tid >> 4) & 7u;
    unsigned t = (tid >> 7) & 2047u;
    unsigned b = tid >> 18;
    const float4* src = (const float4*)(k + (size_t)tid * 8u);
    float4 f0 = src[0], f1 = src[1];
    bf16x8 r;
    r[0] = (__bf16)f0.x; r[1] = (__bf16)f0.y; r[2] = (__bf16)f0.z; r[3] = (__bf16)f0.w;
    r[4] = (__bf16)f1.x; r[5] = (__bf16)f1.y; r[6] = (__bf16)f1.z; r[7] = (__bf16)f1.w;
    unsigned tp = (t & ~31u) | pi32(t & 31u);
    size_t o = ((size_t)((b * 8u + h) * 2048u + tp) * 16u + (s ^ (tp & 7u))) * 8u;
    *(bf16x8*)(kb + o) = r;
}

// ---------------- pre-pass: V convert + transpose to 32-kv tiles ----------------
__global__ __launch_bounds__(256) void cvt_v(const float* __restrict__ v,
                                             unsigned short* __restrict__ vtb) {
    unsigned tid = blockIdx.x * 256u + threadIdx.x;    // 524288 total
    unsigned d = tid & 127u;            // fast-varying => coalesced reads
    unsigned oct = (tid >> 7) & 3u;
    unsigned tile = (tid >> 9) & 63u;
    unsigned kvh = (tid >> 15) & 7u;
    unsigned b = tid >> 18;
    const float* src = v + ((size_t)(b * 2048u + tile * 32u + oct * 8u) * 8u + kvh) * 128u + d;
    bf16x8 r;
#pragma unroll
    for (int e = 0; e < 8; ++e) r[e] = (__bf16)src[(size_t)e * 1024u];
    unsigned p = d >> 1;
    unsigned slot = (d & 1u) * 4u + oct;
    size_t off = (size_t)(b * 8u + kvh) * 262144u + (size_t)tile * 4096u
               + (p * 8u + (slot ^ (p & 7u))) * 8u;
    *(bf16x8*)(vtb + off) = r;
}

// ---------------- main attention kernel ----------------
__device__ inline void load16_lds(const void* g, void* l) {
    __builtin_amdgcn_global_load_lds(
        (__attribute__((address_space(1))) void*)(g),
        (__attribute__((address_space(3))) void*)(l), 16, 0, 0);
}

union BW2 { unsigned u; __bf16 h[2]; };
union BW8 { unsigned u[4]; bf16x8 v; };

__global__ __launch_bounds__(256, 3) void attn_fwd(const float* __restrict__ qg,
                                                   const unsigned short* __restrict__ kb,
                                                   const unsigned short* __restrict__ vtb,
                                                   float* __restrict__ outg) {
    __shared__ __align__(16) unsigned short Kp0[64 * 128], Kp1[64 * 128];  // 2x16KB (2 tiles ea)
    __shared__ __align__(16) unsigned short Vp0[128 * 64], Vp1[128 * 64];  // 2x16KB (2 tiles ea)

    // Decode: bid&7 = XCD = kvh (KV L2-pinned); qtile16 DESCENDING (LPT).
    int bid = blockIdx.x;
    int kvh = bid & 7;
    int pos = bid >> 3;                // 0..127
    int qt = 15 - (pos >> 3);
    int sub = pos & 7;
    int b = sub & 1;
    int h = kvh * 4 + (sub >> 1);

    int tid = threadIdx.x;
    int lane = tid & 63;
    int lq = lane & 31;
    int hi = lane >> 5;
    int q0w = qt * 128 + (tid >> 6) * 32;
    int np = 2 * (qt + 1);             // pair count (nt = 4*(qt+1) tiles, 2 per pass)

    const unsigned short* kT = kb + (size_t)(b * 8 + kvh) * 262144u;
    const unsigned short* vT = vtb + (size_t)(b * 8 + kvh) * 262144u;

    auto stagePair = [&](int u, unsigned short* kd, unsigned short* vd) {
        const char* ks = (const char*)(kT + (size_t)u * 8192u);   // 16 KB contiguous
        const char* vs = (const char*)(vT + (size_t)u * 8192u);   // 16 KB contiguous
#pragma unroll
        for (int i = 0; i < 4; ++i) {
            load16_lds(ks + (i * 256 + tid) * 16, kd + (i * 256 + tid) * 8);
            load16_lds(vs + (i * 256 + tid) * 16, vd + (i * 256 + tid) * 8);
        }
    };

    stagePair(0, Kp0, Vp0);

    // Q B-frags: lane holds q-row = q0w+lq, d-octet (lane>>5) of each 16-chunk.
    bf16x8 qf[8];
    {
        const float* qp = qg + ((size_t)(b * 2048 + q0w + lq) * 32u + h) * 128u;
#pragma unroll
        for (int c = 0; c < 8; ++c) {
            int d0 = c * 16 + hi * 8;
            float4 f0 = *(const float4*)(qp + d0);
            float4 f1 = *(const float4*)(qp + d0 + 4);
            qf[c][0] = (__bf16)(f0.x * QSCALE); qf[c][1] = (__bf16)(f0.y * QSCALE);
            qf[c][2] = (__bf16)(f0.z * QSCALE); qf[c][3] = (__bf16)(f0.w * QSCALE);
            qf[c][4] = (__bf16)(f1.x * QSCALE); qf[c][5] = (__bf16)(f1.y * QSCALE);
            qf[c][6] = (__bf16)(f1.z * QSCALE); qf[c][7] = (__bf16)(f1.w * QSCALE);
        }
    }

    f32x16 acc[4];
#pragma unroll
    for (int dt = 0; dt < 4; ++dt)
#pragma unroll
        for (int r = 0; r < 16; ++r) acc[dt][r] = 0.f;
    float lrun = 0.f;

    unsigned short *kc = Kp0, *kn = Kp1;
    unsigned short *vc = Vp0, *vn = Vp1;

    for (int u = 0; u < np; ++u) {
        // stagePair(u) was issued a full pair-compute phase ago -> near-free wait.
        asm volatile("s_waitcnt vmcnt(0)" ::: "memory");
        __builtin_amdgcn_s_barrier();     // raw barrier: no compiler full drain
        if (u + 1 < np) stagePair(u + 1, kn, vn);   // kn/vn free since pass u-1
        int kv0A = u * 64;
        int kv0B = kv0A + 32;
        if (kv0A <= q0w + 31) {                  // wave-uniform; B active => A active
            bool actB = (kv0B <= q0w + 31);
            // ---- QK^T tile A (8 MFMA) then tile B (8 MFMA, independent)
            f32x16 st0, st1;
#pragma unroll
            for (int r = 0; r < 16; ++r) st0[r] = 0.f;
            __builtin_amdgcn_s_setprio(1);
#pragma unroll
            for (int c = 0; c < 8; ++c) {
                bf16x8 kf = *(const bf16x8*)&kc[lq * 128 + (((2 * c + hi) ^ (lq & 7)) << 3)];
                st0 = __builtin_amdgcn_mfma_f32_32x32x16_bf16(kf, qf[c], st0, 0, 0, 0);
            }
            __builtin_amdgcn_s_setprio(0);
            if (actB) {
#pragma unroll
                for (int r = 0; r < 16; ++r) st1[r] = 0.f;
                __builtin_amdgcn_s_setprio(1);
#pragma unroll
                for (int c = 0; c < 8; ++c) {
                    bf16x8 kf = *(const bf16x8*)&kc[(32 + lq) * 128 + (((2 * c + hi) ^ (lq & 7)) << 3)];
                    st1 = __builtin_amdgcn_mfma_f32_32x32x16_bf16(kf, qf[c], st1, 0, 0, 0);
                }
                __builtin_amdgcn_s_setprio(0);
            }
            // ---- tile A: mask (diag only), softmax, pack, PV  (overlaps QK(B) above)
            if (kv0A == q0w) {
#pragma unroll
                for (int r = 0; r < 16; ++r) {
                    int kvl = (r & 3) + 8 * (r >> 2) + 4 * hi;
                    int q2 = (kvl >> 2) & 3;
                    int kva = (q2 == 1 || q2 == 2) ? (kvl ^ 12) : kvl;
                    if (kva > lq) st0[r] = -1e30f;
                }
            }
#pragma unroll
            for (int r = 0; r < 16; ++r) st0[r] = exp2f(st0[r]);
            {
                BW8 pb0, pb1;
#pragma unroll
                for (int i = 0; i < 4; ++i) {
                    BW2 a; a.h[0] = (__bf16)st0[2 * i];     a.h[1] = (__bf16)st0[2 * i + 1];
                    BW2 c; c.h[0] = (__bf16)st0[8 + 2 * i]; c.h[1] = (__bf16)st0[9 + 2 * i];
                    pb0.u[i] = a.u; pb1.u[i] = c.u;
                }
                __builtin_amdgcn_s_setprio(1);
#pragma unroll
                for (int dt = 0; dt < 4; ++dt) {
                    int drow = dt * 32 + lq;
                    int pp = drow >> 1;
                    int s0 = (drow & 1) * 4 + hi;
                    int s1 = s0 + 2;
                    bf16x8 vf0 = *(const bf16x8*)&vc[pp * 64 + ((s0 ^ (pp & 7)) << 3)];
                    acc[dt] = __builtin_amdgcn_mfma_f32_32x32x16_bf16(vf0, pb0.v, acc[dt], 0, 0, 0);
                    bf16x8 vf1 = *(const bf16x8*)&vc[pp * 64 + ((s1 ^ (pp & 7)) << 3)];
                    acc[dt] = __builtin_amdgcn_mfma_f32_32x32x16_bf16(vf1, pb1.v, acc[dt], 0, 0, 0);
                }
                __builtin_amdgcn_s_setprio(0);
            }
            float s8[8];
#pragma unroll
            for (int i = 0; i < 8; ++i) s8[i] = st0[2 * i] + st0[2 * i + 1];
#pragma unroll
            for (int i = 0; i < 4; ++i) s8[i] = s8[i] + s8[i + 4];
            lrun += (s8[0] + s8[1]) + (s8[2] + s8[3]);
            // ---- tile B: mask, softmax, pack, PV (V at +4096 shorts)
            if (actB) {
                if (kv0B == q0w) {
#pragma unroll
                    for (int r = 0; r < 16; ++r) {
                        int kvl = (r & 3) + 8 * (r >> 2) + 4 * hi;
                        int q2 = (kvl >> 2) & 3;
                        int kva = (q2 == 1 || q2 == 2) ? (kvl ^ 12) : kvl;
                        if (kva > lq) st1[r] = -1e30f;
                    }
                }
#pragma unroll
                for (int r = 0; r < 16; ++r) st1[r] = exp2f(st1[r]);
                BW8 pb0, pb1;
#pragma unroll
                for (int i = 0; i < 4; ++i) {
                    BW2 a; a.h[0] = (__bf16)st1[2 * i];     a.h[1] = (__bf16)st1[2 * i + 1];
                    BW2 c; c.h[0] = (__bf16)st1[8 + 2 * i]; c.h[1] = (__bf16)st1[9 + 2 * i];
                    pb0.u[i] = a.u; pb1.u[i] = c.u;
                }
                __builtin_amdgcn_s_setprio(1);
#pragma unroll
                for (int dt = 0; dt < 4; ++dt) {
                    int drow = dt * 32 + lq;
                    int pp = drow >> 1;
                    int s0 = (drow & 1) * 4 + hi;
                    int s1 = s0 + 2;
                    bf16x8 vf0 = *(const bf16x8*)&vc[4096 + pp * 64 + ((s0 ^ (pp & 7)) << 3)];
                    acc[dt] = __builtin_amdgcn_mfma_f32_32x32x16_bf16(vf0, pb0.v, acc[dt], 0, 0, 0);
                    bf16x8 vf1 = *(const bf16x8*)&vc[4096 + pp * 64 + ((s1 ^ (pp & 7)) << 3)];
                    acc[dt] = __builtin_amdgcn_mfma_f32_32x32x16_bf16(vf1, pb1.v, acc[dt], 0, 0, 0);
                }
                __builtin_amdgcn_s_setprio(0);
                float t8[8];
#pragma unroll
                for (int i = 0; i < 8; ++i) t8[i] = st1[2 * i] + st1[2 * i + 1];
#pragma unroll
                for (int i = 0; i < 4; ++i) t8[i] = t8[i] + t8[i + 4];
                lrun += (t8[0] + t8[1]) + (t8[2] + t8[3]);
            }
        }
        // swap buffer pairs
        unsigned short* tk = kc; kc = kn; kn = tk;
        unsigned short* tv = vc; vc = vn; vn = tv;
    }

    // ---- epilogue: combine lane-halves of lrun once, then 1/l, f32x4 stores
    lrun += __shfl_xor(lrun, 32);
    float il = 1.0f / lrun;
    float* ob = outg + ((size_t)(b * 2048 + q0w + lq) * 32u + h) * 128u;
#pragma unroll
    for (int dt = 0; dt < 4; ++dt)
#pragma unroll
        for (int rq = 0; rq < 4; ++rq) {
            int d = dt * 32 + rq * 8 + hi * 4;
            float4 o4 = { acc[dt][rq * 4 + 0] * il, acc[dt][rq * 4 + 1] * il,
                          acc[dt][rq * 4 + 2] * il, acc[dt][rq * 4 + 3] * il };
            *(float4*)(ob + d) = o4;
        }
}

extern "C" void kernel_launch(void* const* d_in, const int* in_sizes, int n_in,
                              void* d_out, int out_size, void* d_ws, size_t ws_size,
                              hipStream_t stream) {
    const float* q = (const float*)d_in[0];
    const float* k = (const float*)d_in[1];
    const float* v = (const float*)d_in[2];
    float* out = (float*)d_out;
    unsigned short* kbuf = (unsigned short*)d_ws;                    // 8.4 MB bf16 K (pi rows)
    unsigned short* vbuf = kbuf + (size_t)2 * 8 * 2048 * 128;        // 8.4 MB bf16 V^T (32-kv tiles)
    cvt_k<<<2048, 256, 0, stream>>>(k, kbuf);
    cvt_v<<<2048, 256, 0, stream>>>(v, vbuf);
    attn_fwd<<<1024, 256, 0, stream>>>(q, kbuf, vbuf, out);
}